// Round 5
// baseline (441.057 us; speedup 1.0000x reference)
//
#include <hip/hip_runtime.h>
#include <cstddef>

// HVAE tree decoder, fused single kernel. Round 5: ROWS per block 32 -> 16.
// Block = 512 thr (8 waves) = 16 batch rows; each wave owns a 16-col slice
// (1 nt-tile) of N=128, ONE row-tile. Halves per-wave register state
// (ah[4] not ah[2][4], acc 8 not 16) so total regs/wave lands ~<=128 and
// 2-3 blocks of 8 waves co-reside per CU (round-4: 160 regs -> 1 block, 23%
// occupancy, latency-bound on L2 weight loads). LDS ~37KB -> 4 blocks/CU
// LDS-wise; grid = 1024 = exactly 4/CU, no tail.
// No inline asm (cvt_pk NaN'd in r1/r2); scalar f2bf stores; z repacked in ws.
// SH/PSLD must be multiples of 8 shorts (16 B): frag loads are ds_read_b128.

#define BB   16384
#define HH   128
#define OO   32
#define ROWS 16

typedef __attribute__((ext_vector_type(8))) short bf8;
typedef __attribute__((ext_vector_type(4))) float f4;

#define MFMA(a, b, c) __builtin_amdgcn_mfma_f32_16x16x32_bf16(a, b, c, 0, 0, 0)

// packed-weight offsets in ws (shorts)
#define PW_Z2H 0         // [64x128]  -> 8192
#define PW_AWI 8192      // [96x128]  -> 12288
#define PW_AWH 20480     // [384x128] -> 49152
#define PW_FWI 69632     // [96x128]  -> 12288
#define PW_FWH 81920     // [384x128] -> 49152
#define PW_UA  131072    // [128x128] -> 16384
#define PW_UF  147456    // [128x128] -> 16384
#define PW_H2O 163840    // [128x32]  -> 4096
#define PW_END 167936
#define ZBF    167936    // B*64 bf16

#define SH   136   // LDS h row stride (shorts): 272B rows (16B-aligned)
#define PSLD 40    // LDS probs row stride (shorts): 80B rows (16B-aligned)

// bias LDS layout (floats)
#define BA_RZ  0      // abi[0..255]+abh[0..255] (r at +0, z at +128)
#define BA_BH2 256    // abh gate2
#define BA_BI2 384    // abi gate2
#define BF_RZ  512
#define BF_BH2 768
#define BF_BI2 896
#define BU     1024   // uab+ufb
#define BZ2H   1152
#define BH2O   1280   // 32
#define BIAS_N 1312

__device__ __forceinline__ short f2bf(float f) {
  union { float f; unsigned u; } v; v.f = f;
  unsigned r = v.u + 0x7fff + ((v.u >> 16) & 1);   // RNE
  return (short)(r >> 16);
}
__device__ __forceinline__ float bf2f(short h) {
  union { unsigned u; float f; } v;
  v.u = ((unsigned)(unsigned short)h) << 16;
  return v.f;
}
__device__ __forceinline__ float rcp_(float x) { return __builtin_amdgcn_rcpf(x); }
__device__ __forceinline__ float sigmoidf_(float x) { return rcp_(1.0f + __expf(-x)); }
__device__ __forceinline__ float tanhf_(float x) {
  float ax = fabsf(x), e = __expf(-2.0f * ax);
  float t = (1.0f - e) * rcp_(1.0f + e);
  return x >= 0.0f ? t : -t;
}

// ---------------- repack: fp32 [K][N] -> B-frag-major bf16 -------------------
// P[((nt*KC + kc)*64 + lane)*8 + j] = W[kc*32 + (lane>>4)*8 + j][nt*16 + (lane&15)]
template <int K, int N>
__device__ __forceinline__ void repack_one(const float* __restrict__ W,
                                           short* __restrict__ P, int idx) {
  const int KC = K / 32;
  const int j = idx & 7, lane = (idx >> 3) & 63, rest = idx >> 9;
  const int kc = rest % KC, nt = rest / KC;
  const int k = kc * 32 + ((lane >> 4) << 3) + j;
  const int n = nt * 16 + (lane & 15);
  P[idx] = f2bf(W[(size_t)k * N + n]);
}

__global__ __launch_bounds__(256) void k_repack(
    const float* __restrict__ z2hw, const float* __restrict__ awi,
    const float* __restrict__ awh, const float* __restrict__ fwi,
    const float* __restrict__ fwh, const float* __restrict__ uaw,
    const float* __restrict__ ufw, const float* __restrict__ h2ow,
    const float* __restrict__ z, short* __restrict__ ws) {
  const int t = blockIdx.x * 256 + threadIdx.x;
  if (t < PW_AWI)        repack_one<64, 128>(z2hw, ws + PW_Z2H, t - PW_Z2H);
  else if (t < PW_AWH)   repack_one<96, 128>(awi, ws + PW_AWI, t - PW_AWI);
  else if (t < PW_FWI)   repack_one<384, 128>(awh, ws + PW_AWH, t - PW_AWH);
  else if (t < PW_FWH)   repack_one<96, 128>(fwi, ws + PW_FWI, t - PW_FWI);
  else if (t < PW_UA)    repack_one<384, 128>(fwh, ws + PW_FWH, t - PW_FWH);
  else if (t < PW_UF)    repack_one<128, 128>(uaw, ws + PW_UA, t - PW_UA);
  else if (t < PW_H2O)   repack_one<128, 128>(ufw, ws + PW_UF, t - PW_UF);
  else if (t < PW_END)   repack_one<128, 32>(h2ow, ws + PW_H2O, t - PW_H2O);
  else {
    const int i = t - PW_END;
    if (i < BB * 64) ws[ZBF + i] = f2bf(z[i]);
  }
}

// ---------------- slice helpers (wave w owns nt tile w) ----------------------
// Store one 16x16 fragment (rows 0..15, cols w*16..w*16+15).
__device__ __forceinline__ void store_slice16(const f4 hv, short* dst, int lane, int w) {
  const int l15 = lane & 15, q = lane >> 4;
#pragma unroll
  for (int j = 0; j < 4; ++j)
    dst[(q * 4 + j) * SH + w * 16 + l15] = f2bf(hv[j]);
}

// GRU slice (16 cols, 16 rows): x from LDS probs block, h from LDS h block.
__device__ __forceinline__ f4 gru_slice16(const short* xs, const short* hsrc,
                                          const short* wiP, const short* whP,
                                          const float* brz, const float* bh2v,
                                          const float* bi2v,
                                          int lane, int w) {
  const int l15 = lane & 15, q = lane >> 4;
  const int col = w * 16 + l15;
  bf8 ax, ah[4];
  ax = *(const bf8*)(xs + l15 * PSLD + q * 8);
#pragma unroll
  for (int c = 0; c < 4; ++c)
    ah[c] = *(const bf8*)(hsrc + l15 * SH + c * 32 + q * 8);
  const bf8* wi = (const bf8*)wiP;
  const bf8* wh = (const bf8*)whP;
  f4 t2, rg;
  // t2 = bh2 + h@wh2
  {
    const float b = bh2v[col];
    t2 = (f4){b, b, b, b};
  }
  {
    bf8 W[4];
#pragma unroll
    for (int c = 0; c < 4; ++c) W[c] = wh[(w * 12 + 8 + c) * 64 + lane];
#pragma unroll
    for (int c = 0; c < 4; ++c) t2 = MFMA(ah[c], W[c], t2);
  }
  // r gate
  {
    const float b = brz[col];
    rg = (f4){b, b, b, b};
  }
  {
    bf8 Wx = wi[(w * 3 + 0) * 64 + lane];
    bf8 W[4];
#pragma unroll
    for (int c = 0; c < 4; ++c) W[c] = wh[(w * 12 + 0 + c) * 64 + lane];
    rg = MFMA(ax, Wx, rg);
#pragma unroll
    for (int c = 0; c < 4; ++c) rg = MFMA(ah[c], W[c], rg);
  }
#pragma unroll
  for (int j = 0; j < 4; ++j) t2[j] *= sigmoidf_(rg[j]);  // r*(h@wh2+bh2)
  // n preact completes in t2
  {
    const float b = bi2v[col];
#pragma unroll
    for (int j = 0; j < 4; ++j) t2[j] += b;
  }
  {
    bf8 Wx = wi[(w * 3 + 2) * 64 + lane];
    t2 = MFMA(ax, Wx, t2);
  }
  // z gate
  {
    const float b = brz[128 + col];
    rg = (f4){b, b, b, b};
  }
  {
    bf8 Wx = wi[(w * 3 + 1) * 64 + lane];
    bf8 W[4];
#pragma unroll
    for (int c = 0; c < 4; ++c) W[c] = wh[(w * 12 + 4 + c) * 64 + lane];
    rg = MFMA(ax, Wx, rg);
#pragma unroll
    for (int c = 0; c < 4; ++c) rg = MFMA(ah[c], W[c], rg);
  }
  // h' = n + z*(h - n)
  f4 hv;
#pragma unroll
  for (int j = 0; j < 4; ++j) {
    const float hc = bf2f(hsrc[(q * 4 + j) * SH + col]);
    const float zz = sigmoidf_(rg[j]);
    const float nn = tanhf_(t2[j]);
    hv[j] = nn + zz * (hc - nn);
  }
  return hv;
}

// pred (wave 0 only): pred = h@h2o + b for all 16 rows x 32 cols; softmax;
// pred -> LDS spred (fp32), probs -> LDS pstk.
__device__ __forceinline__ void pred_node16(const short* hsrc,
                                            const short* h2oP,
                                            const float* bo,
                                            float* spred, short* pdst,
                                            int lane) {
  const int l15 = lane & 15, q = lane >> 4;
  bf8 a[4];
#pragma unroll
  for (int c = 0; c < 4; ++c)
    a[c] = *(const bf8*)(hsrc + l15 * SH + c * 32 + q * 8);
  const bf8* bw = (const bf8*)h2oP;
  bf8 W[8];
#pragma unroll
  for (int f = 0; f < 8; ++f) W[f] = bw[f * 64 + lane];
  f4 p[2];
#pragma unroll
  for (int nt = 0; nt < 2; ++nt) {
    const float b = bo[nt * 16 + l15];
    f4 acc = (f4){b, b, b, b};
#pragma unroll
    for (int c = 0; c < 4; ++c) acc = MFMA(a[c], W[nt * 4 + c], acc);
    p[nt] = acc;
  }
#pragma unroll
  for (int j = 0; j < 4; ++j) {
    const float v0 = p[0][j], v1 = p[1][j];
    float mx = fmaxf(v0, v1);
#pragma unroll
    for (int s = 1; s < 16; s <<= 1) mx = fmaxf(mx, __shfl_xor(mx, s));
    const float e0 = __expf(v0 - mx), e1 = __expf(v1 - mx);
    float ss = e0 + e1;
#pragma unroll
    for (int s = 1; s < 16; s <<= 1) ss += __shfl_xor(ss, s);
    const float inv = rcp_(ss);
    const int row = q * 4 + j;
    spred[row * 32 + l15] = v0;
    spred[row * 32 + 16 + l15] = v1;
    pdst[row * PSLD + l15] = f2bf(e0 * inv);
    pdst[row * PSLD + 16 + l15] = f2bf(e1 * inv);
  }
}

// preorder schedule, depth 4: type 0=root, 1=left child (gru_a), 2=right child
__device__ const unsigned char d_TYPE[31] =
    {0,1,1,1,1,2,2,1,2,2,1,1,2,2,1,2,2,1,1,1,2,2,1,2,2,1,1,2,2,1,2};
__device__ const unsigned char d_LVL[31] =
    {0,1,2,3,4,4,3,4,4,2,3,4,4,3,4,4,1,2,3,4,4,3,4,4,2,3,4,4,3,4,4};

// ---------------- the fused tree kernel -------------------------------------
__global__ __launch_bounds__(512, 2) void k_tree(
    const short* __restrict__ zbf, const short* __restrict__ pw,
    const float* __restrict__ z2hb, const float* __restrict__ abi,
    const float* __restrict__ abh, const float* __restrict__ fbi,
    const float* __restrict__ fbh, const float* __restrict__ uab,
    const float* __restrict__ ufb, const float* __restrict__ h2ob,
    float* __restrict__ out) {
  __shared__ __align__(16) short hstk[5 * ROWS * SH];   // 21760 B
  __shared__ __align__(16) short hfb[ROWS * SH];        // 4352 B (overlaid: spred)
  __shared__ __align__(16) short pstk[5 * ROWS * PSLD]; // 6400 B
  __shared__ float bias[BIAS_N];                        // 5248 B => 37760 B total
  float* spred = (float*)hfb;                           // 2048 B, lifetime-disjoint
  const int lane = threadIdx.x & 63;
  const int w = threadIdx.x >> 6;
  const int l15 = lane & 15, q = lane >> 4;
  const int col = w * 16 + l15;
  const int r0 = blockIdx.x * ROWS;

  // bias preload: pre-summed where the algorithm always sums them
  for (int t = threadIdx.x; t < BIAS_N; t += 512) {
    float v;
    if (t < 256)       v = abi[t] + abh[t];
    else if (t < 384)  v = abh[t];           // abh gate2
    else if (t < 512)  v = abi[t - 128];     // abi gate2
    else if (t < 768)  v = fbi[t - 512] + fbh[t - 512];
    else if (t < 896)  v = fbh[t - 512];
    else if (t < 1024) v = fbi[t - 640];
    else if (t < 1152) v = uab[t - 1024] + ufb[t - 1024];
    else if (t < 1280) v = z2hb[t - 1152];
    else               v = h2ob[t - 1280];
    bias[t] = v;
  }
  __syncthreads();

  // root: h_in[0] = z @ z2h + b (bf16 z from ws, proven path)
  {
    const bf8* wz = (const bf8*)(pw + PW_Z2H);
    const bf8 W0 = wz[(w * 2 + 0) * 64 + lane];
    const bf8 W1 = wz[(w * 2 + 1) * 64 + lane];
    const float b = bias[BZ2H + col];
    const bf8 az0 = *(const bf8*)(zbf + (size_t)(r0 + l15) * 64 + q * 8);
    const bf8 az1 = *(const bf8*)(zbf + (size_t)(r0 + l15) * 64 + 32 + q * 8);
    f4 acc = (f4){b, b, b, b};
    acc = MFMA(az0, W0, acc);
    acc = MFMA(az1, W1, acc);
    store_slice16(acc, hstk, lane, w);
  }
  __syncthreads();

#pragma unroll 1
  for (int i = 0; i < 31; ++i) {
    const int t = d_TYPE[i];
    const int L = d_LVL[i];
    short* hcur = hstk + L * ROWS * SH;
    short* pcur = pstk + L * ROWS * PSLD;

    if (t == 2) {
      // h_f = gru_f(probs_sib, h_sib)
      const f4 hf = gru_slice16(pcur, hcur, pw + PW_FWI, pw + PW_FWH,
                                bias + BF_RZ, bias + BF_BH2, bias + BF_BI2,
                                lane, w);
      store_slice16(hf, hfb, lane, w);
      __syncthreads();
      // h2 = tanh(h_f@uf + h_par@ua + b)
      const short* hpar = hstk + (L - 1) * ROWS * SH;
      const bf8* uf = (const bf8*)(pw + PW_UF);
      const bf8* ua = (const bf8*)(pw + PW_UA);
      bf8 Wf[4], Wa[4];
#pragma unroll
      for (int c = 0; c < 4; ++c) {
        Wf[c] = uf[(w * 4 + c) * 64 + lane];
        Wa[c] = ua[(w * 4 + c) * 64 + lane];
      }
      const float b = bias[BU + col];
      f4 acc = (f4){b, b, b, b};
#pragma unroll
      for (int c = 0; c < 4; ++c) {
        const bf8 af = *(const bf8*)(hfb + l15 * SH + c * 32 + q * 8);
        const bf8 ap = *(const bf8*)(hpar + l15 * SH + c * 32 + q * 8);
        acc = MFMA(af, Wf[c], acc);
        acc = MFMA(ap, Wa[c], acc);
      }
#pragma unroll
      for (int j = 0; j < 4; ++j) acc[j] = tanhf_(acc[j]);
      store_slice16(acc, hcur, lane, w);
      __syncthreads();
    }

    // pred + softmax: wave 0 handles all 16 rows (both col tiles in-lane)
    if (w == 0)
      pred_node16(hcur, pw + PW_H2O, bias + BH2O, spred, pcur, lane);
    __syncthreads();

    // dump pred: 16 rows x 32 cols fp32 = 2KB contiguous, all 512 threads
    {
      const float v = spred[threadIdx.x];
      __builtin_nontemporal_store(
          v, out + (size_t)i * BB * OO + (size_t)r0 * OO + threadIdx.x);
    }

    // non-leaf: h_in[L+1] = gru_a(probs, h_in[L])
    if (L < 4) {
      const f4 hv = gru_slice16(pcur, hcur, pw + PW_AWI, pw + PW_AWH,
                                bias + BA_RZ, bias + BA_BH2, bias + BA_BI2,
                                lane, w);
      store_slice16(hv, hstk + (L + 1) * ROWS * SH, lane, w);
    }
    // barrier also protects spred (overlaid on hfb) against next node's writes
    __syncthreads();
  }
}

// ---------------- host ------------------------------------------------------
extern "C" void kernel_launch(void* const* d_in, const int* in_sizes, int n_in,
                              void* d_out, int out_size, void* d_ws, size_t ws_size,
                              hipStream_t stream) {
  const float* z    = (const float*)d_in[0];
  const float* z2hw = (const float*)d_in[1];
  const float* z2hb = (const float*)d_in[2];
  const float* h2ow = (const float*)d_in[3];
  const float* h2ob = (const float*)d_in[4];
  const float* awi  = (const float*)d_in[5];
  const float* abi  = (const float*)d_in[6];
  const float* awh  = (const float*)d_in[7];
  const float* abh  = (const float*)d_in[8];
  const float* fwi  = (const float*)d_in[9];
  const float* fbi  = (const float*)d_in[10];
  const float* fwh  = (const float*)d_in[11];
  const float* fbh  = (const float*)d_in[12];
  const float* uaw  = (const float*)d_in[13];
  const float* uab  = (const float*)d_in[14];
  const float* ufw  = (const float*)d_in[15];
  const float* ufb  = (const float*)d_in[16];

  float* out = (float*)d_out;
  short* ws  = (short*)d_ws;

  const int total = PW_END + BB * 64;
  k_repack<<<(total + 255) / 256, 256, 0, stream>>>(
      z2hw, awi, awh, fwi, fwh, uaw, ufw, h2ow, z, ws);

  k_tree<<<BB / ROWS, 512, 0, stream>>>(
      ws + ZBF, ws, z2hb, abi, abh, fbi, fbh, uab, ufb, h2ob, out);
}

// Round 6
// 431.322 us; speedup vs baseline: 1.0226x; 1.0226x over previous
//
#include <hip/hip_runtime.h>
#include <cstddef>

// HVAE tree decoder, fused single kernel. Round 6: 256 thr (4 waves) x ROWS=16;
// each wave owns TWO 16-col nt-tiles (nt0=2w) of N=128, one 16-row tile.
// Why: empirically total regs/wave = arch + ~64 (acc region). 512-thr blocks
// quantize residency at 2 waves/SIMD -> ~148-reg waves waste the 3rd slot
// (r4/r5 stuck at 1 block/CU, 23% occ). 256-thr blocks quantize at 1 wave/SIMD
// -> 3 blocks/CU resident (12 waves/CU) at the same register demand.
// LDS 37.8KB -> 3 blocks fit (113KB < 160K). launch_bounds(256,3): arch cap
// ~170, no spill (r3 proved cap 64 spills; r4 proved cap 128+ is clean).
// z converted in-root via scalar f2bf (no asm — cvt_pk NaN'd in r1/r2);
// k_repack shrinks to weights only. Scalar f2bf LDS stores; rcp activations;
// biases pre-summed in LDS (all proven green r3-r5).
// SH/PSLD must be multiples of 8 shorts (16 B): frag loads are ds_read_b128.

#define BB   16384
#define HH   128
#define OO   32
#define ROWS 16

typedef __attribute__((ext_vector_type(8))) short bf8;
typedef __attribute__((ext_vector_type(4))) float f4;
typedef __attribute__((ext_vector_type(2))) float f2;

#define MFMA(a, b, c) __builtin_amdgcn_mfma_f32_16x16x32_bf16(a, b, c, 0, 0, 0)

// packed-weight offsets in ws (shorts)
#define PW_Z2H 0         // [64x128]  -> 8192
#define PW_AWI 8192      // [96x128]  -> 12288
#define PW_AWH 20480     // [384x128] -> 49152
#define PW_FWI 69632     // [96x128]  -> 12288
#define PW_FWH 81920     // [384x128] -> 49152
#define PW_UA  131072    // [128x128] -> 16384
#define PW_UF  147456    // [128x128] -> 16384
#define PW_H2O 163840    // [128x32]  -> 4096
#define PW_END 167936

#define SH   136   // LDS h row stride (shorts): 272B rows (16B-aligned)
#define PSLD 40    // LDS probs row stride (shorts): 80B rows (16B-aligned)

// bias LDS layout (floats)
#define BA_RZ  0      // abi[0..255]+abh[0..255] (r at +0, z at +128)
#define BA_BH2 256    // abh gate2
#define BA_BI2 384    // abi gate2
#define BF_RZ  512
#define BF_BH2 768
#define BF_BI2 896
#define BU     1024   // uab+ufb
#define BZ2H   1152
#define BH2O   1280   // 32
#define BIAS_N 1312

__device__ __forceinline__ short f2bf(float f) {
  union { float f; unsigned u; } v; v.f = f;
  unsigned r = v.u + 0x7fff + ((v.u >> 16) & 1);   // RNE
  return (short)(r >> 16);
}
__device__ __forceinline__ float bf2f(short h) {
  union { unsigned u; float f; } v;
  v.u = ((unsigned)(unsigned short)h) << 16;
  return v.f;
}
__device__ __forceinline__ float rcp_(float x) { return __builtin_amdgcn_rcpf(x); }
__device__ __forceinline__ float sigmoidf_(float x) { return rcp_(1.0f + __expf(-x)); }
__device__ __forceinline__ float tanhf_(float x) {
  float ax = fabsf(x), e = __expf(-2.0f * ax);
  float t = (1.0f - e) * rcp_(1.0f + e);
  return x >= 0.0f ? t : -t;
}

// ---------------- repack: fp32 [K][N] -> B-frag-major bf16 -------------------
// P[((nt*KC + kc)*64 + lane)*8 + j] = W[kc*32 + (lane>>4)*8 + j][nt*16 + (lane&15)]
template <int K, int N>
__device__ __forceinline__ void repack_one(const float* __restrict__ W,
                                           short* __restrict__ P, int idx) {
  const int KC = K / 32;
  const int j = idx & 7, lane = (idx >> 3) & 63, rest = idx >> 9;
  const int kc = rest % KC, nt = rest / KC;
  const int k = kc * 32 + ((lane >> 4) << 3) + j;
  const int n = nt * 16 + (lane & 15);
  P[idx] = f2bf(W[(size_t)k * N + n]);
}

__global__ __launch_bounds__(256) void k_repack(
    const float* __restrict__ z2hw, const float* __restrict__ awi,
    const float* __restrict__ awh, const float* __restrict__ fwi,
    const float* __restrict__ fwh, const float* __restrict__ uaw,
    const float* __restrict__ ufw, const float* __restrict__ h2ow,
    short* __restrict__ ws) {
  const int t = blockIdx.x * 256 + threadIdx.x;
  if (t < PW_AWI)        repack_one<64, 128>(z2hw, ws + PW_Z2H, t - PW_Z2H);
  else if (t < PW_AWH)   repack_one<96, 128>(awi, ws + PW_AWI, t - PW_AWI);
  else if (t < PW_FWI)   repack_one<384, 128>(awh, ws + PW_AWH, t - PW_AWH);
  else if (t < PW_FWH)   repack_one<96, 128>(fwi, ws + PW_FWI, t - PW_FWI);
  else if (t < PW_UA)    repack_one<384, 128>(fwh, ws + PW_FWH, t - PW_FWH);
  else if (t < PW_UF)    repack_one<128, 128>(uaw, ws + PW_UA, t - PW_UA);
  else if (t < PW_H2O)   repack_one<128, 128>(ufw, ws + PW_UF, t - PW_UF);
  else if (t < PW_END)   repack_one<128, 32>(h2ow, ws + PW_H2O, t - PW_H2O);
}

// ---------------- slice helpers (wave w owns nt tiles 2w, 2w+1) --------------
__device__ __forceinline__ void store_slice(const f4* hv, short* dst, int lane, int w) {
  const int l15 = lane & 15, q = lane >> 4;
  const int nt0 = 2 * w;
#pragma unroll
  for (int n = 0; n < 2; ++n)
#pragma unroll
    for (int j = 0; j < 4; ++j)
      dst[(q * 4 + j) * SH + (nt0 + n) * 16 + l15] = f2bf(hv[n][j]);
}

// GRU slice (32 cols = 2 nt, 16 rows): x from LDS probs, h from LDS h block.
__device__ __forceinline__ void gru_slice(const short* xs, const short* hsrc,
                                          const short* wiP, const short* whP,
                                          const float* brz, const float* bh2v,
                                          const float* bi2v,
                                          int lane, int w, f4* hv) {
  const int l15 = lane & 15, q = lane >> 4;
  const int nt0 = 2 * w;
  const int c0 = nt0 * 16 + l15, c1 = c0 + 16;
  const bf8 ax = *(const bf8*)(xs + l15 * PSLD + q * 8);
  bf8 ah[4];
#pragma unroll
  for (int c = 0; c < 4; ++c)
    ah[c] = *(const bf8*)(hsrc + l15 * SH + c * 32 + q * 8);
  const bf8* wi = (const bf8*)wiP;
  const bf8* wh = (const bf8*)whP;
  f4 t2[2], rg[2];
  // t2 = bh2 + h@wh2
  {
    const float b0 = bh2v[c0], b1 = bh2v[c1];
    t2[0] = (f4){b0, b0, b0, b0};
    t2[1] = (f4){b1, b1, b1, b1};
  }
  {
    bf8 W[8];
#pragma unroll
    for (int f = 0; f < 8; ++f)
      W[f] = wh[((nt0 + (f >> 2)) * 12 + 8 + (f & 3)) * 64 + lane];
#pragma unroll
    for (int f = 0; f < 8; ++f)
      t2[f >> 2] = MFMA(ah[f & 3], W[f], t2[f >> 2]);
  }
  // r gate
  {
    const float b0 = brz[c0], b1 = brz[c1];
    rg[0] = (f4){b0, b0, b0, b0};
    rg[1] = (f4){b1, b1, b1, b1};
  }
  {
    const bf8 Wx0 = wi[(nt0 * 3 + 0) * 64 + lane];
    const bf8 Wx1 = wi[((nt0 + 1) * 3 + 0) * 64 + lane];
    bf8 W[8];
#pragma unroll
    for (int f = 0; f < 8; ++f)
      W[f] = wh[((nt0 + (f >> 2)) * 12 + 0 + (f & 3)) * 64 + lane];
    rg[0] = MFMA(ax, Wx0, rg[0]);
    rg[1] = MFMA(ax, Wx1, rg[1]);
#pragma unroll
    for (int f = 0; f < 8; ++f)
      rg[f >> 2] = MFMA(ah[f & 3], W[f], rg[f >> 2]);
  }
#pragma unroll
  for (int k = 0; k < 2; ++k)
#pragma unroll
    for (int j = 0; j < 4; ++j) t2[k][j] *= sigmoidf_(rg[k][j]);  // r*(h@wh2+bh2)
  // n preact completes in t2
  {
    const float b0 = bi2v[c0], b1 = bi2v[c1];
#pragma unroll
    for (int j = 0; j < 4; ++j) { t2[0][j] += b0; t2[1][j] += b1; }
  }
  {
    const bf8 Wx0 = wi[(nt0 * 3 + 2) * 64 + lane];
    const bf8 Wx1 = wi[((nt0 + 1) * 3 + 2) * 64 + lane];
    t2[0] = MFMA(ax, Wx0, t2[0]);
    t2[1] = MFMA(ax, Wx1, t2[1]);
  }
  // z gate
  {
    const float b0 = brz[128 + c0], b1 = brz[128 + c1];
    rg[0] = (f4){b0, b0, b0, b0};
    rg[1] = (f4){b1, b1, b1, b1};
  }
  {
    const bf8 Wx0 = wi[(nt0 * 3 + 1) * 64 + lane];
    const bf8 Wx1 = wi[((nt0 + 1) * 3 + 1) * 64 + lane];
    bf8 W[8];
#pragma unroll
    for (int f = 0; f < 8; ++f)
      W[f] = wh[((nt0 + (f >> 2)) * 12 + 4 + (f & 3)) * 64 + lane];
    rg[0] = MFMA(ax, Wx0, rg[0]);
    rg[1] = MFMA(ax, Wx1, rg[1]);
#pragma unroll
    for (int f = 0; f < 8; ++f)
      rg[f >> 2] = MFMA(ah[f & 3], W[f], rg[f >> 2]);
  }
  // h' = n + z*(h - n)
#pragma unroll
  for (int n = 0; n < 2; ++n)
#pragma unroll
    for (int j = 0; j < 4; ++j) {
      const float hc = bf2f(hsrc[(q * 4 + j) * SH + (nt0 + n) * 16 + l15]);
      const float zz = sigmoidf_(rg[n][j]);
      const float nn = tanhf_(t2[n][j]);
      hv[n][j] = nn + zz * (hc - nn);
    }
}

// pred (wave 0 only): pred = h@h2o + b for 16 rows x 32 cols; softmax;
// pred -> LDS spred (fp32), probs -> LDS pstk.  (verbatim from green r5)
__device__ __forceinline__ void pred_node16(const short* hsrc,
                                            const short* h2oP,
                                            const float* bo,
                                            float* spred, short* pdst,
                                            int lane) {
  const int l15 = lane & 15, q = lane >> 4;
  bf8 a[4];
#pragma unroll
  for (int c = 0; c < 4; ++c)
    a[c] = *(const bf8*)(hsrc + l15 * SH + c * 32 + q * 8);
  const bf8* bw = (const bf8*)h2oP;
  bf8 W[8];
#pragma unroll
  for (int f = 0; f < 8; ++f) W[f] = bw[f * 64 + lane];
  f4 p[2];
#pragma unroll
  for (int nt = 0; nt < 2; ++nt) {
    const float b = bo[nt * 16 + l15];
    f4 acc = (f4){b, b, b, b};
#pragma unroll
    for (int c = 0; c < 4; ++c) acc = MFMA(a[c], W[nt * 4 + c], acc);
    p[nt] = acc;
  }
#pragma unroll
  for (int j = 0; j < 4; ++j) {
    const float v0 = p[0][j], v1 = p[1][j];
    float mx = fmaxf(v0, v1);
#pragma unroll
    for (int s = 1; s < 16; s <<= 1) mx = fmaxf(mx, __shfl_xor(mx, s));
    const float e0 = __expf(v0 - mx), e1 = __expf(v1 - mx);
    float ss = e0 + e1;
#pragma unroll
    for (int s = 1; s < 16; s <<= 1) ss += __shfl_xor(ss, s);
    const float inv = rcp_(ss);
    const int row = q * 4 + j;
    spred[row * 32 + l15] = v0;
    spred[row * 32 + 16 + l15] = v1;
    pdst[row * PSLD + l15] = f2bf(e0 * inv);
    pdst[row * PSLD + 16 + l15] = f2bf(e1 * inv);
  }
}

// preorder schedule, depth 4: type 0=root, 1=left child (gru_a), 2=right child
__device__ const unsigned char d_TYPE[31] =
    {0,1,1,1,1,2,2,1,2,2,1,1,2,2,1,2,2,1,1,1,2,2,1,2,2,1,1,2,2,1,2};
__device__ const unsigned char d_LVL[31] =
    {0,1,2,3,4,4,3,4,4,2,3,4,4,3,4,4,1,2,3,4,4,3,4,4,2,3,4,4,3,4,4};

// ---------------- the fused tree kernel -------------------------------------
__global__ __launch_bounds__(256, 3) void k_tree(
    const float* __restrict__ zf, const short* __restrict__ pw,
    const float* __restrict__ z2hb, const float* __restrict__ abi,
    const float* __restrict__ abh, const float* __restrict__ fbi,
    const float* __restrict__ fbh, const float* __restrict__ uab,
    const float* __restrict__ ufb, const float* __restrict__ h2ob,
    float* __restrict__ out) {
  __shared__ __align__(16) short hstk[5 * ROWS * SH];   // 21760 B
  __shared__ __align__(16) short hfb[ROWS * SH];        // 4352 B (overlaid: spred)
  __shared__ __align__(16) short pstk[5 * ROWS * PSLD]; // 6400 B
  __shared__ float bias[BIAS_N];                        // 5248 B => 37760 B total
  float* spred = (float*)hfb;                           // 2048 B, lifetime-disjoint
  const int lane = threadIdx.x & 63;
  const int w = threadIdx.x >> 6;        // 4 waves
  const int l15 = lane & 15, q = lane >> 4;
  const int nt0 = 2 * w;
  const int r0 = blockIdx.x * ROWS;

  // bias preload: pre-summed where the algorithm always sums them
  for (int t = threadIdx.x; t < BIAS_N; t += 256) {
    float v;
    if (t < 256)       v = abi[t] + abh[t];
    else if (t < 384)  v = abh[t];           // abh gate2
    else if (t < 512)  v = abi[t - 128];     // abi gate2
    else if (t < 768)  v = fbi[t - 512] + fbh[t - 512];
    else if (t < 896)  v = fbh[t - 512];
    else if (t < 1024) v = fbi[t - 640];
    else if (t < 1152) v = uab[t - 1024] + ufb[t - 1024];
    else if (t < 1280) v = z2hb[t - 1152];
    else               v = h2ob[t - 1280];
    bias[t] = v;
  }
  __syncthreads();

  // root: h_in[0] = z @ z2h + b  (z read as f32, scalar f2bf in-register)
  {
    const bf8* wz = (const bf8*)(pw + PW_Z2H);
    bf8 W[4];
#pragma unroll
    for (int f = 0; f < 4; ++f)
      W[f] = wz[((nt0 + (f >> 1)) * 2 + (f & 1)) * 64 + lane];
    const float* zr = zf + (size_t)(r0 + l15) * 64 + q * 8;
    union { short s[8]; bf8 v; } A0, A1;
    {
      const f4 x0 = *(const f4*)zr, x1 = *(const f4*)(zr + 4);
#pragma unroll
      for (int j = 0; j < 4; ++j) { A0.s[j] = f2bf(x0[j]); A0.s[4 + j] = f2bf(x1[j]); }
      const f4 y0 = *(const f4*)(zr + 32), y1 = *(const f4*)(zr + 36);
#pragma unroll
      for (int j = 0; j < 4; ++j) { A1.s[j] = f2bf(y0[j]); A1.s[4 + j] = f2bf(y1[j]); }
    }
    f4 hv[2];
#pragma unroll
    for (int n = 0; n < 2; ++n) {
      const float b = bias[BZ2H + (nt0 + n) * 16 + l15];
      f4 acc = (f4){b, b, b, b};
      acc = MFMA(A0.v, W[n * 2 + 0], acc);
      acc = MFMA(A1.v, W[n * 2 + 1], acc);
      hv[n] = acc;
    }
    store_slice(hv, hstk, lane, w);
  }
  __syncthreads();

#pragma unroll 1
  for (int i = 0; i < 31; ++i) {
    const int t = d_TYPE[i];
    const int L = d_LVL[i];
    short* hcur = hstk + L * ROWS * SH;
    short* pcur = pstk + L * ROWS * PSLD;

    if (t == 2) {
      // h_f = gru_f(probs_sib, h_sib)
      f4 hf[2];
      gru_slice(pcur, hcur, pw + PW_FWI, pw + PW_FWH,
                bias + BF_RZ, bias + BF_BH2, bias + BF_BI2, lane, w, hf);
      store_slice(hf, hfb, lane, w);
      __syncthreads();
      // h2 = tanh(h_f@uf + h_par@ua + b)
      const short* hpar = hstk + (L - 1) * ROWS * SH;
      const bf8* uf = (const bf8*)(pw + PW_UF);
      const bf8* ua = (const bf8*)(pw + PW_UA);
      bf8 Wf[8], Wa[8];
#pragma unroll
      for (int f = 0; f < 8; ++f) {
        Wf[f] = uf[((nt0 + (f >> 2)) * 4 + (f & 3)) * 64 + lane];
        Wa[f] = ua[((nt0 + (f >> 2)) * 4 + (f & 3)) * 64 + lane];
      }
      bf8 af[4], ap[4];
#pragma unroll
      for (int c = 0; c < 4; ++c) {
        af[c] = *(const bf8*)(hfb + l15 * SH + c * 32 + q * 8);
        ap[c] = *(const bf8*)(hpar + l15 * SH + c * 32 + q * 8);
      }
      f4 hv[2];
#pragma unroll
      for (int n = 0; n < 2; ++n) {
        const float b = bias[BU + (nt0 + n) * 16 + l15];
        hv[n] = (f4){b, b, b, b};
      }
#pragma unroll
      for (int f = 0; f < 8; ++f) {
        hv[f >> 2] = MFMA(af[f & 3], Wf[f], hv[f >> 2]);
        hv[f >> 2] = MFMA(ap[f & 3], Wa[f], hv[f >> 2]);
      }
#pragma unroll
      for (int n = 0; n < 2; ++n)
#pragma unroll
        for (int j = 0; j < 4; ++j) hv[n][j] = tanhf_(hv[n][j]);
      store_slice(hv, hcur, lane, w);
      __syncthreads();
    }

    // pred + softmax: wave 0 handles all 16 rows (both col tiles in-lane)
    if (w == 0)
      pred_node16(hcur, pw + PW_H2O, bias + BH2O, spred, pcur, lane);
    __syncthreads();

    // dump pred: 16 rows x 32 cols fp32 = 2KB contiguous, all 256 threads
    {
      const f2 v = *(const f2*)(spred + threadIdx.x * 2);
      __builtin_nontemporal_store(
          v, (f2*)(out + (size_t)i * BB * OO + (size_t)r0 * OO) + threadIdx.x);
    }

    // non-leaf: h_in[L+1] = gru_a(probs, h_in[L])
    if (L < 4) {
      f4 hv[2];
      gru_slice(pcur, hcur, pw + PW_AWI, pw + PW_AWH,
                bias + BA_RZ, bias + BA_BH2, bias + BA_BI2, lane, w, hv);
      store_slice(hv, hstk + (L + 1) * ROWS * SH, lane, w);
    }
    // barrier also protects spred (overlaid on hfb) against next node's writes
    __syncthreads();
  }
}

// ---------------- host ------------------------------------------------------
extern "C" void kernel_launch(void* const* d_in, const int* in_sizes, int n_in,
                              void* d_out, int out_size, void* d_ws, size_t ws_size,
                              hipStream_t stream) {
  const float* z    = (const float*)d_in[0];
  const float* z2hw = (const float*)d_in[1];
  const float* z2hb = (const float*)d_in[2];
  const float* h2ow = (const float*)d_in[3];
  const float* h2ob = (const float*)d_in[4];
  const float* awi  = (const float*)d_in[5];
  const float* abi  = (const float*)d_in[6];
  const float* awh  = (const float*)d_in[7];
  const float* abh  = (const float*)d_in[8];
  const float* fwi  = (const float*)d_in[9];
  const float* fbi  = (const float*)d_in[10];
  const float* fwh  = (const float*)d_in[11];
  const float* fbh  = (const float*)d_in[12];
  const float* uaw  = (const float*)d_in[13];
  const float* uab  = (const float*)d_in[14];
  const float* ufw  = (const float*)d_in[15];
  const float* ufb  = (const float*)d_in[16];

  float* out = (float*)d_out;
  short* ws  = (short*)d_ws;

  k_repack<<<(PW_END + 255) / 256, 256, 0, stream>>>(
      z2hw, awi, awh, fwi, fwh, uaw, ufw, h2ow, ws);

  k_tree<<<BB / ROWS, 256, 0, stream>>>(
      z, ws, z2hb, abi, abh, fbi, fbh, uab, ufb, h2ob, out);
}

// Round 7
// 270.580 us; speedup vs baseline: 1.6300x; 1.5941x over previous
//
#include <hip/hip_runtime.h>
#include <cstddef>

// HVAE tree decoder, fused single kernel. Round 7: ONE tree-walk per CU.
// Grid = 256 blocks (1/CU), block = 512 thr (8 waves) = 64 batch rows.
// Wave w owns one 16-col nt-tile (w) of N=128 across FOUR 16-row tiles.
// Why: r0-r6 profiling pinned every config at 8 waves/CU (reg granule:
// waves/SIMD = 512/roundup(arch+acc)); per-node time ~9800cyc is L2-weight-
// latency + barriers, not throughput (MfmaUtil 9-13%). r4 paid that chain
// 2x per CU (grid 512); this pays it once (grid 256) and amortizes each
// W-fragment over 4 MFMAs (r4: 2, r6: 1). LDS 135.3KB (<160K) -> 1 block/CU.
// No inline asm (cvt_pk NaN'd r1/r2); scalar f2bf stores; z consumed as f32
// in-root (green r6); rcp activations; biases pre-summed in LDS (green r3-r6).
// SH/PSLD must be multiples of 8 shorts (16 B): frag loads are ds_read_b128.

#define BB   16384
#define HH   128
#define OO   32
#define ROWS 64

typedef __attribute__((ext_vector_type(8))) short bf8;
typedef __attribute__((ext_vector_type(4))) float f4;

#define MFMA(a, b, c) __builtin_amdgcn_mfma_f32_16x16x32_bf16(a, b, c, 0, 0, 0)

// packed-weight offsets in ws (shorts)
#define PW_Z2H 0         // [64x128]  -> 8192
#define PW_AWI 8192      // [96x128]  -> 12288
#define PW_AWH 20480     // [384x128] -> 49152
#define PW_FWI 69632     // [96x128]  -> 12288
#define PW_FWH 81920     // [384x128] -> 49152
#define PW_UA  131072    // [128x128] -> 16384
#define PW_UF  147456    // [128x128] -> 16384
#define PW_H2O 163840    // [128x32]  -> 4096
#define PW_END 167936

#define SH   136   // LDS h row stride (shorts): 272B rows (16B-aligned)
#define PSLD 40    // LDS probs row stride (shorts): 80B rows (16B-aligned)

// bias LDS layout (floats)
#define BA_RZ  0      // abi[0..255]+abh[0..255] (r at +0, z at +128)
#define BA_BH2 256    // abh gate2
#define BA_BI2 384    // abi gate2
#define BF_RZ  512
#define BF_BH2 768
#define BF_BI2 896
#define BU     1024   // uab+ufb
#define BZ2H   1152
#define BH2O   1280   // 32
#define BIAS_N 1312

__device__ __forceinline__ short f2bf(float f) {
  union { float f; unsigned u; } v; v.f = f;
  unsigned r = v.u + 0x7fff + ((v.u >> 16) & 1);   // RNE
  return (short)(r >> 16);
}
__device__ __forceinline__ float bf2f(short h) {
  union { unsigned u; float f; } v;
  v.u = ((unsigned)(unsigned short)h) << 16;
  return v.f;
}
__device__ __forceinline__ float rcp_(float x) { return __builtin_amdgcn_rcpf(x); }
__device__ __forceinline__ float sigmoidf_(float x) { return rcp_(1.0f + __expf(-x)); }
__device__ __forceinline__ float tanhf_(float x) {
  float ax = fabsf(x), e = __expf(-2.0f * ax);
  float t = (1.0f - e) * rcp_(1.0f + e);
  return x >= 0.0f ? t : -t;
}

// ---------------- repack: fp32 [K][N] -> B-frag-major bf16 -------------------
// P[((nt*KC + kc)*64 + lane)*8 + j] = W[kc*32 + (lane>>4)*8 + j][nt*16 + (lane&15)]
template <int K, int N>
__device__ __forceinline__ void repack_one(const float* __restrict__ W,
                                           short* __restrict__ P, int idx) {
  const int KC = K / 32;
  const int j = idx & 7, lane = (idx >> 3) & 63, rest = idx >> 9;
  const int kc = rest % KC, nt = rest / KC;
  const int k = kc * 32 + ((lane >> 4) << 3) + j;
  const int n = nt * 16 + (lane & 15);
  P[idx] = f2bf(W[(size_t)k * N + n]);
}

__global__ __launch_bounds__(256) void k_repack(
    const float* __restrict__ z2hw, const float* __restrict__ awi,
    const float* __restrict__ awh, const float* __restrict__ fwi,
    const float* __restrict__ fwh, const float* __restrict__ uaw,
    const float* __restrict__ ufw, const float* __restrict__ h2ow,
    short* __restrict__ ws) {
  const int t = blockIdx.x * 256 + threadIdx.x;
  if (t < PW_AWI)        repack_one<64, 128>(z2hw, ws + PW_Z2H, t - PW_Z2H);
  else if (t < PW_AWH)   repack_one<96, 128>(awi, ws + PW_AWI, t - PW_AWI);
  else if (t < PW_FWI)   repack_one<384, 128>(awh, ws + PW_AWH, t - PW_AWH);
  else if (t < PW_FWH)   repack_one<96, 128>(fwi, ws + PW_FWI, t - PW_FWI);
  else if (t < PW_UA)    repack_one<384, 128>(fwh, ws + PW_FWH, t - PW_FWH);
  else if (t < PW_UF)    repack_one<128, 128>(uaw, ws + PW_UA, t - PW_UA);
  else if (t < PW_H2O)   repack_one<128, 128>(ufw, ws + PW_UF, t - PW_UF);
  else if (t < PW_END)   repack_one<128, 32>(h2ow, ws + PW_H2O, t - PW_H2O);
}

// ---------------- slice helpers (wave w owns nt tile w; 4 row-tiles) ---------
__device__ __forceinline__ void store_slice(const f4* hv, short* dst, int lane, int w) {
  const int l15 = lane & 15, q = lane >> 4;
#pragma unroll
  for (int rt = 0; rt < 4; ++rt)
#pragma unroll
    for (int j = 0; j < 4; ++j)
      dst[(rt * 16 + q * 4 + j) * SH + w * 16 + l15] = f2bf(hv[rt][j]);
}

// GRU slice (16 cols, 64 rows): x from LDS probs block, h from LDS h block.
__device__ __forceinline__ void gru_slice(const short* xs, const short* hsrc,
                                          const short* wiP, const short* whP,
                                          const float* brz, const float* bh2v,
                                          const float* bi2v,
                                          int lane, int w, f4* hv) {
  const int l15 = lane & 15, q = lane >> 4;
  const int col = w * 16 + l15;
  bf8 ax[4], ah[4][4];
#pragma unroll
  for (int rt = 0; rt < 4; ++rt) {
    ax[rt] = *(const bf8*)(xs + (rt * 16 + l15) * PSLD + q * 8);
#pragma unroll
    for (int c = 0; c < 4; ++c)
      ah[rt][c] = *(const bf8*)(hsrc + (rt * 16 + l15) * SH + c * 32 + q * 8);
  }
  const bf8* wi = (const bf8*)wiP;
  const bf8* wh = (const bf8*)whP;
  f4 t2[4], rg[4];
  // t2 = bh2 + h@wh2
  {
    const float b = bh2v[col];
#pragma unroll
    for (int rt = 0; rt < 4; ++rt) t2[rt] = (f4){b, b, b, b};
  }
  {
    bf8 W[4];
#pragma unroll
    for (int c = 0; c < 4; ++c) W[c] = wh[(w * 12 + 8 + c) * 64 + lane];
#pragma unroll
    for (int c = 0; c < 4; ++c)
#pragma unroll
      for (int rt = 0; rt < 4; ++rt) t2[rt] = MFMA(ah[rt][c], W[c], t2[rt]);
  }
  // r gate
  {
    const float b = brz[col];
#pragma unroll
    for (int rt = 0; rt < 4; ++rt) rg[rt] = (f4){b, b, b, b};
  }
  {
    bf8 Wx = wi[(w * 3 + 0) * 64 + lane];
    bf8 W[4];
#pragma unroll
    for (int c = 0; c < 4; ++c) W[c] = wh[(w * 12 + 0 + c) * 64 + lane];
#pragma unroll
    for (int rt = 0; rt < 4; ++rt) rg[rt] = MFMA(ax[rt], Wx, rg[rt]);
#pragma unroll
    for (int c = 0; c < 4; ++c)
#pragma unroll
      for (int rt = 0; rt < 4; ++rt) rg[rt] = MFMA(ah[rt][c], W[c], rg[rt]);
  }
#pragma unroll
  for (int k = 0; k < 4; ++k)
#pragma unroll
    for (int j = 0; j < 4; ++j) t2[k][j] *= sigmoidf_(rg[k][j]);  // r*(h@wh2+bh2)
  // n preact completes in t2
  {
    const float b = bi2v[col];
#pragma unroll
    for (int k = 0; k < 4; ++k)
#pragma unroll
      for (int j = 0; j < 4; ++j) t2[k][j] += b;
  }
  {
    bf8 Wx = wi[(w * 3 + 2) * 64 + lane];
#pragma unroll
    for (int rt = 0; rt < 4; ++rt) t2[rt] = MFMA(ax[rt], Wx, t2[rt]);
  }
  // z gate
  {
    const float b = brz[128 + col];
#pragma unroll
    for (int rt = 0; rt < 4; ++rt) rg[rt] = (f4){b, b, b, b};
  }
  {
    bf8 Wx = wi[(w * 3 + 1) * 64 + lane];
    bf8 W[4];
#pragma unroll
    for (int c = 0; c < 4; ++c) W[c] = wh[(w * 12 + 4 + c) * 64 + lane];
#pragma unroll
    for (int rt = 0; rt < 4; ++rt) rg[rt] = MFMA(ax[rt], Wx, rg[rt]);
#pragma unroll
    for (int c = 0; c < 4; ++c)
#pragma unroll
      for (int rt = 0; rt < 4; ++rt) rg[rt] = MFMA(ah[rt][c], W[c], rg[rt]);
  }
  // h' = n + z*(h - n)
#pragma unroll
  for (int rt = 0; rt < 4; ++rt)
#pragma unroll
    for (int j = 0; j < 4; ++j) {
      const float hc = bf2f(hsrc[(rt * 16 + q * 4 + j) * SH + col]);
      const float zz = sigmoidf_(rg[rt][j]);
      const float nn = tanhf_(t2[rt][j]);
      hv[rt][j] = nn + zz * (hc - nn);
    }
}

// pred for row-tile w (waves 0..3): pred = h@h2o + b; softmax;
// pred -> LDS spred (fp32), probs -> LDS pstk.  (verbatim r4 green body)
__device__ __forceinline__ void pred_node16(const short* hsrc,
                                            const short* h2oP,
                                            const float* bo,
                                            float* spred, short* pdst,
                                            int lane, int w) {
  const int l15 = lane & 15, q = lane >> 4;
  bf8 a[4];
#pragma unroll
  for (int c = 0; c < 4; ++c)
    a[c] = *(const bf8*)(hsrc + (w * 16 + l15) * SH + c * 32 + q * 8);
  const bf8* bw = (const bf8*)h2oP;
  bf8 W[8];
#pragma unroll
  for (int f = 0; f < 8; ++f) W[f] = bw[f * 64 + lane];
  f4 p[2];
#pragma unroll
  for (int nt = 0; nt < 2; ++nt) {
    const float b = bo[nt * 16 + l15];
    f4 acc = (f4){b, b, b, b};
#pragma unroll
    for (int c = 0; c < 4; ++c) acc = MFMA(a[c], W[nt * 4 + c], acc);
    p[nt] = acc;
  }
#pragma unroll
  for (int j = 0; j < 4; ++j) {
    const float v0 = p[0][j], v1 = p[1][j];
    float mx = fmaxf(v0, v1);
#pragma unroll
    for (int s = 1; s < 16; s <<= 1) mx = fmaxf(mx, __shfl_xor(mx, s));
    const float e0 = __expf(v0 - mx), e1 = __expf(v1 - mx);
    float ss = e0 + e1;
#pragma unroll
    for (int s = 1; s < 16; s <<= 1) ss += __shfl_xor(ss, s);
    const float inv = rcp_(ss);
    const int row = w * 16 + q * 4 + j;
    spred[row * 32 + l15] = v0;
    spred[row * 32 + 16 + l15] = v1;
    pdst[row * PSLD + l15] = f2bf(e0 * inv);
    pdst[row * PSLD + 16 + l15] = f2bf(e1 * inv);
  }
}

// preorder schedule, depth 4: type 0=root, 1=left child (gru_a), 2=right child
__device__ const unsigned char d_TYPE[31] =
    {0,1,1,1,1,2,2,1,2,2,1,1,2,2,1,2,2,1,1,1,2,2,1,2,2,1,1,2,2,1,2};
__device__ const unsigned char d_LVL[31] =
    {0,1,2,3,4,4,3,4,4,2,3,4,4,3,4,4,1,2,3,4,4,3,4,4,2,3,4,4,3,4,4};

// ---------------- the fused tree kernel -------------------------------------
__global__ __launch_bounds__(512, 2) void k_tree(
    const float* __restrict__ zf, const short* __restrict__ pw,
    const float* __restrict__ z2hb, const float* __restrict__ abi,
    const float* __restrict__ abh, const float* __restrict__ fbi,
    const float* __restrict__ fbh, const float* __restrict__ uab,
    const float* __restrict__ ufb, const float* __restrict__ h2ob,
    float* __restrict__ out) {
  __shared__ __align__(16) short hstk[5 * ROWS * SH];   // 87040 B
  __shared__ __align__(16) short hfb[ROWS * SH];        // 17408 B (overlaid: spred)
  __shared__ __align__(16) short pstk[5 * ROWS * PSLD]; // 25600 B
  __shared__ float bias[BIAS_N];                        // 5248 B => 135296 B total
  float* spred = (float*)hfb;                           // 8192 B, lifetime-disjoint
  const int lane = threadIdx.x & 63;
  const int w = threadIdx.x >> 6;        // 8 waves, wave w owns nt tile w
  const int l15 = lane & 15, q = lane >> 4;
  const int col = w * 16 + l15;
  const int r0 = blockIdx.x * ROWS;

  // bias preload: pre-summed where the algorithm always sums them
  for (int t = threadIdx.x; t < BIAS_N; t += 512) {
    float v;
    if (t < 256)       v = abi[t] + abh[t];
    else if (t < 384)  v = abh[t];           // abh gate2
    else if (t < 512)  v = abi[t - 128];     // abi gate2
    else if (t < 768)  v = fbi[t - 512] + fbh[t - 512];
    else if (t < 896)  v = fbh[t - 512];
    else if (t < 1024) v = fbi[t - 640];
    else if (t < 1152) v = uab[t - 1024] + ufb[t - 1024];
    else if (t < 1280) v = z2hb[t - 1152];
    else               v = h2ob[t - 1280];
    bias[t] = v;
  }
  __syncthreads();

  // root: h_in[0] = z @ z2h + b  (z read as f32, scalar f2bf in-register)
  {
    const bf8* wz = (const bf8*)(pw + PW_Z2H);
    const bf8 W0 = wz[(w * 2 + 0) * 64 + lane];
    const bf8 W1 = wz[(w * 2 + 1) * 64 + lane];
    const float b = bias[BZ2H + col];
    f4 hv[4];
#pragma unroll
    for (int rt = 0; rt < 4; ++rt) {
      const float* zr = zf + (size_t)(r0 + rt * 16 + l15) * 64 + q * 8;
      union { short s[8]; bf8 v; } A0, A1;
      {
        const f4 x0 = *(const f4*)zr, x1 = *(const f4*)(zr + 4);
#pragma unroll
        for (int j = 0; j < 4; ++j) { A0.s[j] = f2bf(x0[j]); A0.s[4 + j] = f2bf(x1[j]); }
        const f4 y0 = *(const f4*)(zr + 32), y1 = *(const f4*)(zr + 36);
#pragma unroll
        for (int j = 0; j < 4; ++j) { A1.s[j] = f2bf(y0[j]); A1.s[4 + j] = f2bf(y1[j]); }
      }
      f4 acc = (f4){b, b, b, b};
      acc = MFMA(A0.v, W0, acc);
      acc = MFMA(A1.v, W1, acc);
      hv[rt] = acc;
    }
    store_slice(hv, hstk, lane, w);
  }
  __syncthreads();

#pragma unroll 1
  for (int i = 0; i < 31; ++i) {
    const int t = d_TYPE[i];
    const int L = d_LVL[i];
    short* hcur = hstk + L * ROWS * SH;
    short* pcur = pstk + L * ROWS * PSLD;

    if (t == 2) {
      // h_f = gru_f(probs_sib, h_sib)
      f4 hf[4];
      gru_slice(pcur, hcur, pw + PW_FWI, pw + PW_FWH,
                bias + BF_RZ, bias + BF_BH2, bias + BF_BI2, lane, w, hf);
      store_slice(hf, hfb, lane, w);
      __syncthreads();
      // h2 = tanh(h_f@uf + h_par@ua + b)
      const short* hpar = hstk + (L - 1) * ROWS * SH;
      const bf8* uf = (const bf8*)(pw + PW_UF);
      const bf8* ua = (const bf8*)(pw + PW_UA);
      bf8 Wf[4], Wa[4];
#pragma unroll
      for (int c = 0; c < 4; ++c) {
        Wf[c] = uf[(w * 4 + c) * 64 + lane];
        Wa[c] = ua[(w * 4 + c) * 64 + lane];
      }
      const float b = bias[BU + col];
      f4 hv[4];
#pragma unroll
      for (int rt = 0; rt < 4; ++rt) {
        f4 acc = (f4){b, b, b, b};
#pragma unroll
        for (int c = 0; c < 4; ++c) {
          const bf8 af = *(const bf8*)(hfb + (rt * 16 + l15) * SH + c * 32 + q * 8);
          const bf8 ap = *(const bf8*)(hpar + (rt * 16 + l15) * SH + c * 32 + q * 8);
          acc = MFMA(af, Wf[c], acc);
          acc = MFMA(ap, Wa[c], acc);
        }
#pragma unroll
        for (int j = 0; j < 4; ++j) acc[j] = tanhf_(acc[j]);
        hv[rt] = acc;
      }
      store_slice(hv, hcur, lane, w);
      __syncthreads();
    }

    // pred + softmax: waves 0..3 each handle one 16-row tile
    if (w < 4)
      pred_node16(hcur, pw + PW_H2O, bias + BH2O, spred, pcur, lane, w);
    __syncthreads();

    // dump pred: 64 rows x 32 cols fp32 = 8KB contiguous, all 512 threads
    {
      const f4 v = *(const f4*)(spred + threadIdx.x * 4);
      __builtin_nontemporal_store(
          v, (f4*)(out + (size_t)i * BB * OO + (size_t)r0 * OO) + threadIdx.x);
    }

    // non-leaf: h_in[L+1] = gru_a(probs, h_in[L])
    if (L < 4) {
      f4 hv[4];
      gru_slice(pcur, hcur, pw + PW_AWI, pw + PW_AWH,
                bias + BA_RZ, bias + BA_BH2, bias + BA_BI2, lane, w, hv);
      store_slice(hv, hstk + (L + 1) * ROWS * SH, lane, w);
    }
    // barrier also protects spred (overlaid on hfb) against next node's writes
    __syncthreads();
  }
}

// ---------------- host ------------------------------------------------------
extern "C" void kernel_launch(void* const* d_in, const int* in_sizes, int n_in,
                              void* d_out, int out_size, void* d_ws, size_t ws_size,
                              hipStream_t stream) {
  const float* z    = (const float*)d_in[0];
  const float* z2hw = (const float*)d_in[1];
  const float* z2hb = (const float*)d_in[2];
  const float* h2ow = (const float*)d_in[3];
  const float* h2ob = (const float*)d_in[4];
  const float* awi  = (const float*)d_in[5];
  const float* abi  = (const float*)d_in[6];
  const float* awh  = (const float*)d_in[7];
  const float* abh  = (const float*)d_in[8];
  const float* fwi  = (const float*)d_in[9];
  const float* fbi  = (const float*)d_in[10];
  const float* fwh  = (const float*)d_in[11];
  const float* fbh  = (const float*)d_in[12];
  const float* uaw  = (const float*)d_in[13];
  const float* uab  = (const float*)d_in[14];
  const float* ufw  = (const float*)d_in[15];
  const float* ufb  = (const float*)d_in[16];

  float* out = (float*)d_out;
  short* ws  = (short*)d_ws;

  k_repack<<<(PW_END + 255) / 256, 256, 0, stream>>>(
      z2hw, awi, awh, fwi, fwh, uaw, ufw, h2ow, ws);

  k_tree<<<BB / ROWS, 512, 0, stream>>>(
      z, ws, z2hb, abi, abh, fbi, fbh, uab, ufb, h2ob, out);
}